// Round 1
// baseline (4739.492 us; speedup 1.0000x reference)
//
#include <hip/hip_runtime.h>

#define NPn 100000
#define NSn 10000
#define EMBn 256
#define HIDn 128
#define NEn 500000
#define NLn 200000

// async global->LDS: per-lane global src, wave-uniform LDS dest (+lane*16B)
__device__ __forceinline__ void gl_lds16(const float* g, float* l) {
  __builtin_amdgcn_global_load_lds(
      (const __attribute__((address_space(1))) void*)g,
      (__attribute__((address_space(3))) void*)l, 16, 0, 0);
}

// ---------------- degree histogram ----------------
__global__ void k_hist(const int* __restrict__ es, const int* __restrict__ ed,
                       int* __restrict__ dp, int* __restrict__ dsw) {
  const int stride = gridDim.x * blockDim.x;
  for (int i = blockIdx.x * blockDim.x + threadIdx.x; i < NEn; i += stride) {
    atomicAdd(&dp[es[i]], 1);
    atomicAdd(&dsw[ed[i]], 1);
  }
}

// ---------------- scatter-add rows: agg[dst[e]] += X[src[e]] ----------------
__global__ void k_scatter(const float* __restrict__ X, const int* __restrict__ src,
                          const int* __restrict__ dst, float* __restrict__ agg) {
  const int stride = gridDim.x * blockDim.x;
  const int n = NEn * 32;
  for (int i = blockIdx.x * blockDim.x + threadIdx.x; i < n; i += stride) {
    const int e = i >> 5, q = i & 31;
    const int s = src[e], d = dst[e];
    const float4 v = ((const float4*)X)[(size_t)s * 32 + q];
    float* a = agg + (size_t)d * 128 + q * 4;
    unsafeAtomicAdd(a + 0, v.x);
    unsafeAtomicAdd(a + 1, v.y);
    unsafeAtomicAdd(a + 2, v.z);
    unsafeAtomicAdd(a + 3, v.w);
  }
}

// ---------------- out[m] = X[m]@W + b + emb[ids[m]]  (X:[M,256], W:[256,128]) ----------------
__global__ __launch_bounds__(256) void k_input(const float* __restrict__ X,
    const float* __restrict__ W, const float* __restrict__ b,
    const float* __restrict__ emb, const int* __restrict__ ids,
    float* __restrict__ out, int M) {
  __shared__ float xs[32 * 256];
  const int t = threadIdx.x, c = t & 127, g = t >> 7;
  const int lane = t & 63, wv = t >> 6;
  const float bc = b[c];
  const int ntiles = (M + 31) >> 5;
  for (int tile = blockIdx.x; tile < ntiles; tile += gridDim.x) {
    const int row0 = tile << 5;
#pragma unroll
    for (int r = 0; r < 8; ++r) {
      int row = row0 + wv * 8 + r;
      row = row < M ? row : M - 1;
      gl_lds16(X + (size_t)row * 256 + lane * 4, xs + (wv * 8 + r) * 256);
    }
    asm volatile("s_waitcnt vmcnt(0)" ::: "memory");
    __syncthreads();
    float acc[16];
#pragma unroll
    for (int r = 0; r < 16; ++r) acc[r] = 0.f;
    const float4* xr = (const float4*)(xs + g * 16 * 256);
#pragma unroll 2
    for (int k4 = 0; k4 < 64; ++k4) {
      const float w0 = W[(k4 * 4 + 0) * 128 + c];
      const float w1 = W[(k4 * 4 + 1) * 128 + c];
      const float w2 = W[(k4 * 4 + 2) * 128 + c];
      const float w3 = W[(k4 * 4 + 3) * 128 + c];
#pragma unroll
      for (int r = 0; r < 16; ++r) {
        const float4 xv = xr[r * 64 + k4];
        acc[r] = fmaf(xv.w, w3, fmaf(xv.z, w2, fmaf(xv.y, w1, fmaf(xv.x, w0, acc[r]))));
      }
    }
    __syncthreads();
#pragma unroll
    for (int r = 0; r < 16; ++r) {
      const int row = row0 + g * 16 + r;
      if (row < M)
        out[(size_t)row * 128 + c] = acc[r] + bc + emb[(size_t)ids[row] * 128 + c];
    }
  }
}

// ---------------- out[m] = (AGG[m]/max(deg,1))@Wl + Xd[m]@Wr + b, opt relu ----------------
__global__ __launch_bounds__(256) void k_sage(const float* __restrict__ AGG,
    const int* __restrict__ DEG, const float* __restrict__ Xd,
    const float* __restrict__ Wl, const float* __restrict__ Wr,
    const float* __restrict__ b, float* __restrict__ out, int M, int dorelu) {
  __shared__ float xs[32 * 256];  // row = [agg(128) | x(128)]
  const int t = threadIdx.x, c = t & 127, g = t >> 7;
  const int lane = t & 63, wv = t >> 6;
  const float bc = b[c];
  const int ntiles = (M + 31) >> 5;
  for (int tile = blockIdx.x; tile < ntiles; tile += gridDim.x) {
    const int row0 = tile << 5;
#pragma unroll
    for (int r = 0; r < 8; ++r) {
      int row = row0 + wv * 8 + r;
      row = row < M ? row : M - 1;
      const float* src = (lane < 32)
          ? AGG + (size_t)row * 128 + lane * 4
          : Xd + (size_t)row * 128 + (lane - 32) * 4;
      gl_lds16(src, xs + (wv * 8 + r) * 256);
    }
    asm volatile("s_waitcnt vmcnt(0)" ::: "memory");
    __syncthreads();
    float acc[16];
#pragma unroll
    for (int r = 0; r < 16; ++r) acc[r] = 0.f;
    const float4* xr = (const float4*)(xs + g * 16 * 256);
#pragma unroll 2
    for (int k4 = 0; k4 < 32; ++k4) {   // agg half -> Wl
      const float w0 = Wl[(k4 * 4 + 0) * 128 + c];
      const float w1 = Wl[(k4 * 4 + 1) * 128 + c];
      const float w2 = Wl[(k4 * 4 + 2) * 128 + c];
      const float w3 = Wl[(k4 * 4 + 3) * 128 + c];
#pragma unroll
      for (int r = 0; r < 16; ++r) {
        const float4 xv = xr[r * 64 + k4];
        acc[r] = fmaf(xv.w, w3, fmaf(xv.z, w2, fmaf(xv.y, w1, fmaf(xv.x, w0, acc[r]))));
      }
    }
    // fold the mean's 1/deg into the Wl partial (linearity)
#pragma unroll
    for (int r = 0; r < 16; ++r) {
      int row = row0 + g * 16 + r;
      row = row < M ? row : M - 1;
      acc[r] *= 1.0f / fmaxf((float)DEG[row], 1.0f);
    }
#pragma unroll 2
    for (int k4 = 32; k4 < 64; ++k4) {  // x half -> Wr
      const float w0 = Wr[((k4 - 32) * 4 + 0) * 128 + c];
      const float w1 = Wr[((k4 - 32) * 4 + 1) * 128 + c];
      const float w2 = Wr[((k4 - 32) * 4 + 2) * 128 + c];
      const float w3 = Wr[((k4 - 32) * 4 + 3) * 128 + c];
#pragma unroll
      for (int r = 0; r < 16; ++r) {
        const float4 xv = xr[r * 64 + k4];
        acc[r] = fmaf(xv.w, w3, fmaf(xv.z, w2, fmaf(xv.y, w1, fmaf(xv.x, w0, acc[r]))));
      }
    }
    __syncthreads();
#pragma unroll
    for (int r = 0; r < 16; ++r) {
      const int row = row0 + g * 16 + r;
      if (row < M) {
        float v = acc[r] + bc;
        if (dorelu) v = fmaxf(v, 0.f);
        out[(size_t)row * 128 + c] = v;
      }
    }
  }
}

// ---------------- out[l] = W2 . relu(concat(OP[LP[l]],OS[LS[l]])@W + b1) + b2 ----------------
__global__ __launch_bounds__(256) void k_cls(const float* __restrict__ OP,
    const float* __restrict__ OS, const int* __restrict__ LP,
    const int* __restrict__ LS, const float* __restrict__ W,
    const float* __restrict__ b1, const float* __restrict__ W2,
    const float* __restrict__ b2, float* __restrict__ out, int M) {
  __shared__ float xs[32 * 256];  // row = [o_p(128) | o_s(128)]
  __shared__ float part[64];
  const int t = threadIdx.x, c = t & 127;
  const int lane = t & 63, wv = t >> 6;
  const int g = t >> 7;
  const float bcc = b1[c], w2c = W2[c], b2v = b2[0];
  const int ntiles = (M + 31) >> 5;
  for (int tile = blockIdx.x; tile < ntiles; tile += gridDim.x) {
    const int row0 = tile << 5;
#pragma unroll
    for (int r = 0; r < 8; ++r) {
      int row = row0 + wv * 8 + r;
      row = row < M ? row : M - 1;
      const float* src = (lane < 32)
          ? OP + (size_t)LP[row] * 128 + lane * 4
          : OS + (size_t)LS[row] * 128 + (lane - 32) * 4;
      gl_lds16(src, xs + (wv * 8 + r) * 256);
    }
    asm volatile("s_waitcnt vmcnt(0)" ::: "memory");
    __syncthreads();
    float acc[16];
#pragma unroll
    for (int r = 0; r < 16; ++r) acc[r] = 0.f;
    const float4* xr = (const float4*)(xs + g * 16 * 256);
#pragma unroll 2
    for (int k4 = 0; k4 < 64; ++k4) {
      const float w0 = W[(k4 * 4 + 0) * 128 + c];
      const float w1 = W[(k4 * 4 + 1) * 128 + c];
      const float w2 = W[(k4 * 4 + 2) * 128 + c];
      const float w3 = W[(k4 * 4 + 3) * 128 + c];
#pragma unroll
      for (int r = 0; r < 16; ++r) {
        const float4 xv = xr[r * 64 + k4];
        acc[r] = fmaf(xv.w, w3, fmaf(xv.z, w2, fmaf(xv.y, w1, fmaf(xv.x, w0, acc[r]))));
      }
    }
    __syncthreads();  // xs reads done; part reuse safe across tiles
    // h = relu(acc + b1); v = h * W2[c]; reduce over c (2 waves per row-group)
#pragma unroll
    for (int r = 0; r < 16; ++r) {
      float v = fmaxf(acc[r] + bcc, 0.f) * w2c;
#pragma unroll
      for (int off = 32; off >= 1; off >>= 1) v += __shfl_xor(v, off);
      if (lane == 0) part[wv * 16 + r] = v;
    }
    __syncthreads();
    if (t < 32) {
      const int gg = t >> 4, r = t & 15;
      const int row = row0 + gg * 16 + r;
      if (row < M) out[row] = part[gg * 32 + r] + part[gg * 32 + 16 + r] + b2v;
    }
    __syncthreads();
  }
}

extern "C" void kernel_launch(void* const* d_in, const int* in_sizes, int n_in,
                              void* d_out, int out_size, void* d_ws, size_t ws_size,
                              hipStream_t stream) {
  const float* x_paper     = (const float*)d_in[0];
  const float* x_software  = (const float*)d_in[1];
  const int*   paper_id    = (const int*)d_in[2];
  const int*   software_id = (const int*)d_in[3];
  const int*   edge_src    = (const int*)d_in[4];
  const int*   edge_dst    = (const int*)d_in[5];
  const int*   lbl_paper   = (const int*)d_in[6];
  const int*   lbl_soft    = (const int*)d_in[7];
  const float* paper_emb   = (const float*)d_in[8];
  const float* soft_emb    = (const float*)d_in[9];
  const float* Wp = (const float*)d_in[10]; const float* bp = (const float*)d_in[11];
  const float* Ws = (const float*)d_in[12]; const float* bs = (const float*)d_in[13];
  const float* Wl1_ps = (const float*)d_in[14]; const float* bl1_ps = (const float*)d_in[15];
  const float* Wr1_ps = (const float*)d_in[16];
  const float* Wl1_sp = (const float*)d_in[17]; const float* bl1_sp = (const float*)d_in[18];
  const float* Wr1_sp = (const float*)d_in[19];
  const float* Wl2_ps = (const float*)d_in[20]; const float* bl2_ps = (const float*)d_in[21];
  const float* Wr2_ps = (const float*)d_in[22];
  const float* Wl2_sp = (const float*)d_in[23]; const float* bl2_sp = (const float*)d_in[24];
  const float* Wr2_sp = (const float*)d_in[25];
  const float* Wc1 = (const float*)d_in[26]; const float* bc1 = (const float*)d_in[27];
  const float* Wc2 = (const float*)d_in[28]; const float* bc2 = (const float*)d_in[29];
  float* outp = (float*)d_out;

  // workspace layout (floats): x_p/o_p, x_s/o_s, h_p, h_s, agg_p, agg_s, deg_p, deg_s
  float* ws    = (float*)d_ws;
  float* x_p   = ws;                 // 12,800,000  (reused as o_p)
  float* x_s   = ws + 12800000;      //  1,280,000  (reused as o_s)
  float* h_p   = ws + 14080000;      // 12,800,000
  float* h_s   = ws + 26880000;      //  1,280,000
  float* agg_p = ws + 28160000;      // 12,800,000
  float* agg_s = ws + 40960000;      //  1,280,000
  int*   deg_p = (int*)(ws + 42240000);  // 100,000
  int*   deg_s = (int*)(ws + 42340000);  //  10,000
  float* o_p = x_p;
  float* o_s = x_s;

  // zero agg_p..deg_s (contiguous): (12.8M+1.28M+0.1M+0.01M)*4 bytes
  hipMemsetAsync(agg_p, 0, (size_t)14190000 * 4, stream);
  k_hist<<<1024, 256, 0, stream>>>(edge_src, edge_dst, deg_p, deg_s);

  // input fusion
  k_input<<<1024, 256, 0, stream>>>(x_paper, Wp, bp, paper_emb, paper_id, x_p, NPn);
  k_input<<<313, 256, 0, stream>>>(x_software, Ws, bs, soft_emb, software_id, x_s, NSn);

  // layer 1
  k_scatter<<<8192, 256, 0, stream>>>(x_p, edge_src, edge_dst, agg_s);
  k_scatter<<<8192, 256, 0, stream>>>(x_s, edge_dst, edge_src, agg_p);
  k_sage<<<313, 256, 0, stream>>>(agg_s, deg_s, x_s, Wl1_ps, Wr1_ps, bl1_ps, h_s, NSn, 1);
  k_sage<<<1024, 256, 0, stream>>>(agg_p, deg_p, x_p, Wl1_sp, Wr1_sp, bl1_sp, h_p, NPn, 1);

  // layer 2 (re-zero agg only; deg unchanged)
  hipMemsetAsync(agg_p, 0, (size_t)14080000 * 4, stream);
  k_scatter<<<8192, 256, 0, stream>>>(h_p, edge_src, edge_dst, agg_s);
  k_scatter<<<8192, 256, 0, stream>>>(h_s, edge_dst, edge_src, agg_p);
  k_sage<<<313, 256, 0, stream>>>(agg_s, deg_s, h_s, Wl2_ps, Wr2_ps, bl2_ps, o_s, NSn, 0);
  k_sage<<<1024, 256, 0, stream>>>(agg_p, deg_p, h_p, Wl2_sp, Wr2_sp, bl2_sp, o_p, NPn, 0);

  // classifier
  k_cls<<<1024, 256, 0, stream>>>(o_p, o_s, lbl_paper, lbl_soft, Wc1, bc1, Wc2, bc2,
                                  outp, NLn);
}

// Round 2
// 1502.844 us; speedup vs baseline: 3.1537x; 3.1537x over previous
//
#include <hip/hip_runtime.h>

#define NPn 100000
#define NSn 10000
#define EMBn 256
#define HIDn 128
#define NEn 500000
#define NLn 200000

// async global->LDS: per-lane global src, wave-uniform LDS dest (+lane*16B)
__device__ __forceinline__ void gl_lds16(const float* g, float* l) {
  __builtin_amdgcn_global_load_lds(
      (const __attribute__((address_space(1))) void*)g,
      (__attribute__((address_space(3))) void*)l, 16, 0, 0);
}

// ---------------- degree histogram ----------------
__global__ void k_hist(const int* __restrict__ es, const int* __restrict__ ed,
                       int* __restrict__ dp, int* __restrict__ dsw) {
  const int stride = gridDim.x * blockDim.x;
  for (int i = blockIdx.x * blockDim.x + threadIdx.x; i < NEn; i += stride) {
    atomicAdd(&dp[es[i]], 1);
    atomicAdd(&dsw[ed[i]], 1);
  }
}

// ---------------- scan pass 1: per-block exclusive scan + block totals ----------------
__global__ __launch_bounds__(1024) void k_scan1(const int* __restrict__ deg, int n,
    int* __restrict__ off, int* __restrict__ bsum) {
  __shared__ int wsum[16];
  const int t = threadIdx.x, lane = t & 63, w = t >> 6;
  const int i = blockIdx.x * 1024 + t;
  const int v = (i < n) ? deg[i] : 0;
  int x = v;
#pragma unroll
  for (int o = 1; o < 64; o <<= 1) { int y = __shfl_up(x, o); if (lane >= o) x += y; }
  if (lane == 63) wsum[w] = x;
  __syncthreads();
  if (t < 16) {
    int s = wsum[t];
#pragma unroll
    for (int o = 1; o < 16; o <<= 1) { int y = __shfl_up(s, o); if (t >= o) s += y; }
    wsum[t] = s;
  }
  __syncthreads();
  const int excl = (x - v) + (w ? wsum[w - 1] : 0);
  if (i < n) off[i] = excl;
  if (t == 1023) bsum[blockIdx.x] = excl + v;  // block total
}

// ---------------- scan pass 2: single-block exclusive scan of block sums ----------------
__global__ __launch_bounds__(1024) void k_scan2(int* __restrict__ bsum, int nb,
    int* __restrict__ off, int n) {
  __shared__ int wsum[16];
  const int t = threadIdx.x, lane = t & 63, w = t >> 6;
  const int v = (t < nb) ? bsum[t] : 0;
  int x = v;
#pragma unroll
  for (int o = 1; o < 64; o <<= 1) { int y = __shfl_up(x, o); if (lane >= o) x += y; }
  if (lane == 63) wsum[w] = x;
  __syncthreads();
  if (t < 16) {
    int s = wsum[t];
#pragma unroll
    for (int o = 1; o < 16; o <<= 1) { int y = __shfl_up(s, o); if (t >= o) s += y; }
    wsum[t] = s;
  }
  __syncthreads();
  const int excl = (x - v) + (w ? wsum[w - 1] : 0);
  if (t < nb) bsum[t] = excl;
  if (t == nb - 1) off[n] = excl + v;  // grand total = NEn
}

// ---------------- scan pass 3: add block bases; init cursors ----------------
__global__ void k_scan3(int* __restrict__ off, int* __restrict__ cur,
                        const int* __restrict__ bsum, int n) {
  const int i = blockIdx.x * blockDim.x + threadIdx.x;
  if (i < n) {
    const int o = off[i] + bsum[i >> 10];
    off[i] = o;
    cur[i] = o;
  }
}

// ---------------- CSR fill (both directions in one pass) ----------------
__global__ void k_fill(const int* __restrict__ es, const int* __restrict__ ed,
                       int* __restrict__ cur_p, int* __restrict__ cur_s,
                       int* __restrict__ csr_p, int* __restrict__ csr_s) {
  const int stride = gridDim.x * blockDim.x;
  for (int e = blockIdx.x * blockDim.x + threadIdx.x; e < NEn; e += stride) {
    const int s = es[e], d = ed[e];
    const int ps = atomicAdd(&cur_s[d], 1);
    csr_s[ps] = s;
    const int pp = atomicAdd(&cur_p[s], 1);
    csr_p[pp] = d;
  }
}

// ------- gather-aggregate: agg[d] = mean_{e in CSR[d]} X[lst[e]]  (pre-normalized) -------
__global__ __launch_bounds__(256) void k_gather(const float* __restrict__ X,
    const int* __restrict__ off, const int* __restrict__ lst,
    float* __restrict__ agg, int n) {
  const int q = threadIdx.x & 31;
  const int g0 = (blockIdx.x * blockDim.x + threadIdx.x) >> 5;
  const int gs = (gridDim.x * blockDim.x) >> 5;
  for (int d = g0; d < n; d += gs) {
    const int s0 = off[d], s1 = off[d + 1];
    float4 a0 = make_float4(0.f, 0.f, 0.f, 0.f);
    float4 a1 = make_float4(0.f, 0.f, 0.f, 0.f);
    int e = s0;
    for (; e + 2 <= s1; e += 2) {
      const int sa = lst[e], sb = lst[e + 1];
      const float4 va = ((const float4*)X)[(size_t)sa * 32 + q];
      const float4 vb = ((const float4*)X)[(size_t)sb * 32 + q];
      a0.x += va.x; a0.y += va.y; a0.z += va.z; a0.w += va.w;
      a1.x += vb.x; a1.y += vb.y; a1.z += vb.z; a1.w += vb.w;
    }
    if (e < s1) {
      const int sa = lst[e];
      const float4 va = ((const float4*)X)[(size_t)sa * 32 + q];
      a0.x += va.x; a0.y += va.y; a0.z += va.z; a0.w += va.w;
    }
    const int dg = s1 - s0;
    const float inv = 1.0f / (float)(dg > 1 ? dg : 1);
    float4 r;
    r.x = (a0.x + a1.x) * inv; r.y = (a0.y + a1.y) * inv;
    r.z = (a0.z + a1.z) * inv; r.w = (a0.w + a1.w) * inv;
    ((float4*)agg)[(size_t)d * 32 + q] = r;
  }
}

// ---------------- out[m] = X[m]@W + b + emb[ids[m]]  (X:[M,256], W:[256,128]) ----------------
__global__ __launch_bounds__(256) void k_input(const float* __restrict__ X,
    const float* __restrict__ W, const float* __restrict__ b,
    const float* __restrict__ emb, const int* __restrict__ ids,
    float* __restrict__ out, int M) {
  __shared__ float xs[32 * 256];
  const int t = threadIdx.x, c = t & 127, g = t >> 7;
  const int lane = t & 63, wv = t >> 6;
  const float bc = b[c];
  const int ntiles = (M + 31) >> 5;
  for (int tile = blockIdx.x; tile < ntiles; tile += gridDim.x) {
    const int row0 = tile << 5;
#pragma unroll
    for (int r = 0; r < 8; ++r) {
      int row = row0 + wv * 8 + r;
      row = row < M ? row : M - 1;
      gl_lds16(X + (size_t)row * 256 + lane * 4, xs + (wv * 8 + r) * 256);
    }
    asm volatile("s_waitcnt vmcnt(0)" ::: "memory");
    __syncthreads();
    float acc[16];
#pragma unroll
    for (int r = 0; r < 16; ++r) acc[r] = 0.f;
    const float4* xr = (const float4*)(xs + g * 16 * 256);
#pragma unroll 2
    for (int k4 = 0; k4 < 64; ++k4) {
      const float w0 = W[(k4 * 4 + 0) * 128 + c];
      const float w1 = W[(k4 * 4 + 1) * 128 + c];
      const float w2 = W[(k4 * 4 + 2) * 128 + c];
      const float w3 = W[(k4 * 4 + 3) * 128 + c];
#pragma unroll
      for (int r = 0; r < 16; ++r) {
        const float4 xv = xr[r * 64 + k4];
        acc[r] = fmaf(xv.w, w3, fmaf(xv.z, w2, fmaf(xv.y, w1, fmaf(xv.x, w0, acc[r]))));
      }
    }
    __syncthreads();
#pragma unroll
    for (int r = 0; r < 16; ++r) {
      const int row = row0 + g * 16 + r;
      if (row < M)
        out[(size_t)row * 128 + c] = acc[r] + bc + emb[(size_t)ids[row] * 128 + c];
    }
  }
}

// ------- out[m] = AGG[m]@Wl + Xd[m]@Wr + b, opt relu (AGG pre-normalized) -------
__global__ __launch_bounds__(256) void k_sage(const float* __restrict__ AGG,
    const float* __restrict__ Xd, const float* __restrict__ Wl,
    const float* __restrict__ Wr, const float* __restrict__ b,
    float* __restrict__ out, int M, int dorelu) {
  __shared__ float xs[32 * 256];  // row = [agg(128) | x(128)]
  const int t = threadIdx.x, c = t & 127, g = t >> 7;
  const int lane = t & 63, wv = t >> 6;
  const float bc = b[c];
  const int ntiles = (M + 31) >> 5;
  for (int tile = blockIdx.x; tile < ntiles; tile += gridDim.x) {
    const int row0 = tile << 5;
#pragma unroll
    for (int r = 0; r < 8; ++r) {
      int row = row0 + wv * 8 + r;
      row = row < M ? row : M - 1;
      const float* src = (lane < 32)
          ? AGG + (size_t)row * 128 + lane * 4
          : Xd + (size_t)row * 128 + (lane - 32) * 4;
      gl_lds16(src, xs + (wv * 8 + r) * 256);
    }
    asm volatile("s_waitcnt vmcnt(0)" ::: "memory");
    __syncthreads();
    float acc[16];
#pragma unroll
    for (int r = 0; r < 16; ++r) acc[r] = 0.f;
    const float4* xr = (const float4*)(xs + g * 16 * 256);
#pragma unroll 2
    for (int k4 = 0; k4 < 32; ++k4) {   // agg half -> Wl
      const float w0 = Wl[(k4 * 4 + 0) * 128 + c];
      const float w1 = Wl[(k4 * 4 + 1) * 128 + c];
      const float w2 = Wl[(k4 * 4 + 2) * 128 + c];
      const float w3 = Wl[(k4 * 4 + 3) * 128 + c];
#pragma unroll
      for (int r = 0; r < 16; ++r) {
        const float4 xv = xr[r * 64 + k4];
        acc[r] = fmaf(xv.w, w3, fmaf(xv.z, w2, fmaf(xv.y, w1, fmaf(xv.x, w0, acc[r]))));
      }
    }
#pragma unroll 2
    for (int k4 = 32; k4 < 64; ++k4) {  // x half -> Wr
      const float w0 = Wr[((k4 - 32) * 4 + 0) * 128 + c];
      const float w1 = Wr[((k4 - 32) * 4 + 1) * 128 + c];
      const float w2 = Wr[((k4 - 32) * 4 + 2) * 128 + c];
      const float w3 = Wr[((k4 - 32) * 4 + 3) * 128 + c];
#pragma unroll
      for (int r = 0; r < 16; ++r) {
        const float4 xv = xr[r * 64 + k4];
        acc[r] = fmaf(xv.w, w3, fmaf(xv.z, w2, fmaf(xv.y, w1, fmaf(xv.x, w0, acc[r]))));
      }
    }
    __syncthreads();
#pragma unroll
    for (int r = 0; r < 16; ++r) {
      const int row = row0 + g * 16 + r;
      if (row < M) {
        float v = acc[r] + bc;
        if (dorelu) v = fmaxf(v, 0.f);
        out[(size_t)row * 128 + c] = v;
      }
    }
  }
}

// ---------------- out[l] = W2 . relu(concat(OP[LP[l]],OS[LS[l]])@W + b1) + b2 ----------------
__global__ __launch_bounds__(256) void k_cls(const float* __restrict__ OP,
    const float* __restrict__ OS, const int* __restrict__ LP,
    const int* __restrict__ LS, const float* __restrict__ W,
    const float* __restrict__ b1, const float* __restrict__ W2,
    const float* __restrict__ b2, float* __restrict__ out, int M) {
  __shared__ float xs[32 * 256];  // row = [o_p(128) | o_s(128)]
  __shared__ float part[64];
  const int t = threadIdx.x, c = t & 127;
  const int lane = t & 63, wv = t >> 6;
  const int g = t >> 7;
  const float bcc = b1[c], w2c = W2[c], b2v = b2[0];
  const int ntiles = (M + 31) >> 5;
  for (int tile = blockIdx.x; tile < ntiles; tile += gridDim.x) {
    const int row0 = tile << 5;
#pragma unroll
    for (int r = 0; r < 8; ++r) {
      int row = row0 + wv * 8 + r;
      row = row < M ? row : M - 1;
      const float* src = (lane < 32)
          ? OP + (size_t)LP[row] * 128 + lane * 4
          : OS + (size_t)LS[row] * 128 + (lane - 32) * 4;
      gl_lds16(src, xs + (wv * 8 + r) * 256);
    }
    asm volatile("s_waitcnt vmcnt(0)" ::: "memory");
    __syncthreads();
    float acc[16];
#pragma unroll
    for (int r = 0; r < 16; ++r) acc[r] = 0.f;
    const float4* xr = (const float4*)(xs + g * 16 * 256);
#pragma unroll 2
    for (int k4 = 0; k4 < 64; ++k4) {
      const float w0 = W[(k4 * 4 + 0) * 128 + c];
      const float w1 = W[(k4 * 4 + 1) * 128 + c];
      const float w2 = W[(k4 * 4 + 2) * 128 + c];
      const float w3 = W[(k4 * 4 + 3) * 128 + c];
#pragma unroll
      for (int r = 0; r < 16; ++r) {
        const float4 xv = xr[r * 64 + k4];
        acc[r] = fmaf(xv.w, w3, fmaf(xv.z, w2, fmaf(xv.y, w1, fmaf(xv.x, w0, acc[r]))));
      }
    }
    __syncthreads();  // xs reads done; part reuse safe across tiles
#pragma unroll
    for (int r = 0; r < 16; ++r) {
      float v = fmaxf(acc[r] + bcc, 0.f) * w2c;
#pragma unroll
      for (int off = 32; off >= 1; off >>= 1) v += __shfl_xor(v, off);
      if (lane == 0) part[wv * 16 + r] = v;
    }
    __syncthreads();
    if (t < 32) {
      const int gg = t >> 4, r = t & 15;
      const int row = row0 + gg * 16 + r;
      if (row < M) out[row] = part[gg * 32 + r] + part[gg * 32 + 16 + r] + b2v;
    }
    __syncthreads();
  }
}

extern "C" void kernel_launch(void* const* d_in, const int* in_sizes, int n_in,
                              void* d_out, int out_size, void* d_ws, size_t ws_size,
                              hipStream_t stream) {
  const float* x_paper     = (const float*)d_in[0];
  const float* x_software  = (const float*)d_in[1];
  const int*   paper_id    = (const int*)d_in[2];
  const int*   software_id = (const int*)d_in[3];
  const int*   edge_src    = (const int*)d_in[4];
  const int*   edge_dst    = (const int*)d_in[5];
  const int*   lbl_paper   = (const int*)d_in[6];
  const int*   lbl_soft    = (const int*)d_in[7];
  const float* paper_emb   = (const float*)d_in[8];
  const float* soft_emb    = (const float*)d_in[9];
  const float* Wp = (const float*)d_in[10]; const float* bp = (const float*)d_in[11];
  const float* Ws = (const float*)d_in[12]; const float* bs = (const float*)d_in[13];
  const float* Wl1_ps = (const float*)d_in[14]; const float* bl1_ps = (const float*)d_in[15];
  const float* Wr1_ps = (const float*)d_in[16];
  const float* Wl1_sp = (const float*)d_in[17]; const float* bl1_sp = (const float*)d_in[18];
  const float* Wr1_sp = (const float*)d_in[19];
  const float* Wl2_ps = (const float*)d_in[20]; const float* bl2_ps = (const float*)d_in[21];
  const float* Wr2_ps = (const float*)d_in[22];
  const float* Wl2_sp = (const float*)d_in[23]; const float* bl2_sp = (const float*)d_in[24];
  const float* Wr2_sp = (const float*)d_in[25];
  const float* Wc1 = (const float*)d_in[26]; const float* bc1 = (const float*)d_in[27];
  const float* Wc2 = (const float*)d_in[28]; const float* bc2 = (const float*)d_in[29];
  float* outp = (float*)d_out;

  // workspace layout (floats)
  float* ws    = (float*)d_ws;
  float* x_p   = ws;                 // 12,800,000  (reused as o_p)
  float* x_s   = ws + 12800000;      //  1,280,000  (reused as o_s)
  float* h_p   = ws + 14080000;      // 12,800,000
  float* h_s   = ws + 26880000;      //  1,280,000
  float* agg_p = ws + 28160000;      // 12,800,000
  float* agg_s = ws + 40960000;      //  1,280,000  -> ends 42,240,000
  int*   deg_p = (int*)(ws + 42240000);  // 100,000 (aliased as cur_p after scan)
  int*   deg_s = deg_p + 100000;         //  10,000 (aliased as cur_s)
  int*   off_p = deg_s + 10000;          // 100,001
  int*   off_s = off_p + 100001;         //  10,001
  int*   bsum  = off_s + 10001;          //   1,024
  int*   csr_p = bsum + 1024;            // 500,000 (dst ids grouped by paper src)
  int*   csr_s = csr_p + 500000;         // 500,000 (src ids grouped by software dst)
  float* o_p = x_p;
  float* o_s = x_s;

  // ---- CSR build (once; reused by both layers) ----
  hipMemsetAsync(deg_p, 0, (size_t)110000 * 4, stream);  // deg_p + deg_s contiguous
  k_hist<<<1024, 256, 0, stream>>>(edge_src, edge_dst, deg_p, deg_s);
  k_scan1<<<98, 1024, 0, stream>>>(deg_p, NPn, off_p, bsum);
  k_scan2<<<1, 1024, 0, stream>>>(bsum, 98, off_p, NPn);
  k_scan3<<<391, 256, 0, stream>>>(off_p, deg_p, bsum, NPn);   // cur_p := deg_p
  k_scan1<<<10, 1024, 0, stream>>>(deg_s, NSn, off_s, bsum);
  k_scan2<<<1, 1024, 0, stream>>>(bsum, 10, off_s, NSn);
  k_scan3<<<40, 256, 0, stream>>>(off_s, deg_s, bsum, NSn);    // cur_s := deg_s
  k_fill<<<1024, 256, 0, stream>>>(edge_src, edge_dst, deg_p, deg_s, csr_p, csr_s);

  // ---- input fusion ----
  k_input<<<1024, 256, 0, stream>>>(x_paper, Wp, bp, paper_emb, paper_id, x_p, NPn);
  k_input<<<313, 256, 0, stream>>>(x_software, Ws, bs, soft_emb, software_id, x_s, NSn);

  // ---- layer 1 (gather-aggregate, pre-normalized) ----
  k_gather<<<1250, 256, 0, stream>>>(x_p, off_s, csr_s, agg_s, NSn);
  k_gather<<<4096, 256, 0, stream>>>(x_s, off_p, csr_p, agg_p, NPn);
  k_sage<<<313, 256, 0, stream>>>(agg_s, x_s, Wl1_ps, Wr1_ps, bl1_ps, h_s, NSn, 1);
  k_sage<<<1024, 256, 0, stream>>>(agg_p, x_p, Wl1_sp, Wr1_sp, bl1_sp, h_p, NPn, 1);

  // ---- layer 2 ----
  k_gather<<<1250, 256, 0, stream>>>(h_p, off_s, csr_s, agg_s, NSn);
  k_gather<<<4096, 256, 0, stream>>>(h_s, off_p, csr_p, agg_p, NPn);
  k_sage<<<313, 256, 0, stream>>>(agg_s, h_s, Wl2_ps, Wr2_ps, bl2_ps, o_s, NSn, 0);
  k_sage<<<1024, 256, 0, stream>>>(agg_p, h_p, Wl2_sp, Wr2_sp, bl2_sp, o_p, NPn, 0);

  // ---- classifier ----
  k_cls<<<1024, 256, 0, stream>>>(o_p, o_s, lbl_paper, lbl_soft, Wc1, bc1, Wc2, bc2,
                                  outp, NLn);
}

// Round 3
// 1175.413 us; speedup vs baseline: 4.0322x; 1.2786x over previous
//
#include <hip/hip_runtime.h>

#define NPn 100000
#define NSn 10000
#define EMBn 256
#define HIDn 128
#define NEn 500000
#define NLn 200000

// async global->LDS: per-lane global src, wave-uniform LDS dest (+lane*16B)
__device__ __forceinline__ void gl_lds16(const float* g, float* l) {
  __builtin_amdgcn_global_load_lds(
      (const __attribute__((address_space(1))) void*)g,
      (__attribute__((address_space(3))) void*)l, 16, 0, 0);
}

__device__ __forceinline__ float4 f4fma(float s, float4 w, float4 a) {
  a.x = fmaf(s, w.x, a.x); a.y = fmaf(s, w.y, a.y);
  a.z = fmaf(s, w.z, a.z); a.w = fmaf(s, w.w, a.w);
  return a;
}

// ---------------- degree histogram ----------------
__global__ void k_hist(const int* __restrict__ es, const int* __restrict__ ed,
                       int* __restrict__ dp, int* __restrict__ dsw) {
  const int stride = gridDim.x * blockDim.x;
  for (int i = blockIdx.x * blockDim.x + threadIdx.x; i < NEn; i += stride) {
    atomicAdd(&dp[es[i]], 1);
    atomicAdd(&dsw[ed[i]], 1);
  }
}

// ---------------- scan pass 1: per-block exclusive scan + block totals ----------------
__global__ __launch_bounds__(1024) void k_scan1(const int* __restrict__ deg, int n,
    int* __restrict__ off, int* __restrict__ bsum) {
  __shared__ int wsum[16];
  const int t = threadIdx.x, lane = t & 63, w = t >> 6;
  const int i = blockIdx.x * 1024 + t;
  const int v = (i < n) ? deg[i] : 0;
  int x = v;
#pragma unroll
  for (int o = 1; o < 64; o <<= 1) { int y = __shfl_up(x, o); if (lane >= o) x += y; }
  if (lane == 63) wsum[w] = x;
  __syncthreads();
  if (t < 16) {
    int s = wsum[t];
#pragma unroll
    for (int o = 1; o < 16; o <<= 1) { int y = __shfl_up(s, o); if (t >= o) s += y; }
    wsum[t] = s;
  }
  __syncthreads();
  const int excl = (x - v) + (w ? wsum[w - 1] : 0);
  if (i < n) off[i] = excl;
  if (t == 1023) bsum[blockIdx.x] = excl + v;  // block total
}

// ---------------- scan pass 2: single-block exclusive scan of block sums ----------------
__global__ __launch_bounds__(1024) void k_scan2(int* __restrict__ bsum, int nb,
    int* __restrict__ off, int n) {
  __shared__ int wsum[16];
  const int t = threadIdx.x, lane = t & 63, w = t >> 6;
  const int v = (t < nb) ? bsum[t] : 0;
  int x = v;
#pragma unroll
  for (int o = 1; o < 64; o <<= 1) { int y = __shfl_up(x, o); if (lane >= o) x += y; }
  if (lane == 63) wsum[w] = x;
  __syncthreads();
  if (t < 16) {
    int s = wsum[t];
#pragma unroll
    for (int o = 1; o < 16; o <<= 1) { int y = __shfl_up(s, o); if (t >= o) s += y; }
    wsum[t] = s;
  }
  __syncthreads();
  const int excl = (x - v) + (w ? wsum[w - 1] : 0);
  if (t < nb) bsum[t] = excl;
  if (t == nb - 1) off[n] = excl + v;  // grand total = NEn
}

// ---------------- scan pass 3: add block bases; init cursors ----------------
__global__ void k_scan3(int* __restrict__ off, int* __restrict__ cur,
                        const int* __restrict__ bsum, int n) {
  const int i = blockIdx.x * blockDim.x + threadIdx.x;
  if (i < n) {
    const int o = off[i] + bsum[i >> 10];
    off[i] = o;
    cur[i] = o;
  }
}

// ---------------- CSR fill (both directions in one pass) ----------------
__global__ void k_fill(const int* __restrict__ es, const int* __restrict__ ed,
                       int* __restrict__ cur_p, int* __restrict__ cur_s,
                       int* __restrict__ csr_p, int* __restrict__ csr_s) {
  const int stride = gridDim.x * blockDim.x;
  for (int e = blockIdx.x * blockDim.x + threadIdx.x; e < NEn; e += stride) {
    const int s = es[e], d = ed[e];
    const int ps = atomicAdd(&cur_s[d], 1);
    csr_s[ps] = s;
    const int pp = atomicAdd(&cur_p[s], 1);
    csr_p[pp] = d;
  }
}

// ------- gather-aggregate: agg[d] = mean_{e in CSR[d]} X[lst[e]]  (pre-normalized) -------
__global__ __launch_bounds__(256) void k_gather(const float* __restrict__ X,
    const int* __restrict__ off, const int* __restrict__ lst,
    float* __restrict__ agg, int n) {
  const int q = threadIdx.x & 31;
  const int g0 = (blockIdx.x * blockDim.x + threadIdx.x) >> 5;
  const int gs = (gridDim.x * blockDim.x) >> 5;
  for (int d = g0; d < n; d += gs) {
    const int s0 = off[d], s1 = off[d + 1];
    float4 a0 = make_float4(0.f, 0.f, 0.f, 0.f);
    float4 a1 = make_float4(0.f, 0.f, 0.f, 0.f);
    int e = s0;
    for (; e + 2 <= s1; e += 2) {
      const int sa = lst[e], sb = lst[e + 1];
      const float4 va = ((const float4*)X)[(size_t)sa * 32 + q];
      const float4 vb = ((const float4*)X)[(size_t)sb * 32 + q];
      a0.x += va.x; a0.y += va.y; a0.z += va.z; a0.w += va.w;
      a1.x += vb.x; a1.y += vb.y; a1.z += vb.z; a1.w += vb.w;
    }
    if (e < s1) {
      const int sa = lst[e];
      const float4 va = ((const float4*)X)[(size_t)sa * 32 + q];
      a0.x += va.x; a0.y += va.y; a0.z += va.z; a0.w += va.w;
    }
    const int dg = s1 - s0;
    const float inv = 1.0f / (float)(dg > 1 ? dg : 1);
    float4 r;
    r.x = (a0.x + a1.x) * inv; r.y = (a0.y + a1.y) * inv;
    r.z = (a0.z + a1.z) * inv; r.w = (a0.w + a1.w) * inv;
    ((float4*)agg)[(size_t)d * 32 + q] = r;
  }
}

// ============ GEMM kernels: 32-row tile, thread = 4 rows x 4 cols ============
// t: cg = t&31 -> cols 4cg..4cg+3 (float4), rg = t>>5 -> rows 4rg..4rg+3.
// Per k4: 4 ds_read_b128 (broadcast, conflict-free) + 4 coalesced W float4 + 64 FMA.

// ---------------- out[m] = X[m]@W + b + emb[ids[m]]  (X:[M,256], W:[256,128]) ----------------
__global__ __launch_bounds__(256) void k_input(const float* __restrict__ X,
    const float* __restrict__ W, const float* __restrict__ b,
    const float* __restrict__ emb, const int* __restrict__ ids,
    float* __restrict__ out, int M) {
  __shared__ float xs[32 * 256];
  const int t = threadIdx.x, cg = t & 31, rg = t >> 5;
  const int lane = t & 63, wv = t >> 6;
  const float4 bq = *(const float4*)(b + 4 * cg);
  const int ntiles = (M + 31) >> 5;
  for (int tile = blockIdx.x; tile < ntiles; tile += gridDim.x) {
    const int row0 = tile << 5;
#pragma unroll
    for (int r = 0; r < 8; ++r) {
      int row = row0 + wv * 8 + r;
      row = row < M ? row : M - 1;
      gl_lds16(X + (size_t)row * 256 + lane * 4, xs + (wv * 8 + r) * 256);
    }
    asm volatile("s_waitcnt vmcnt(0)" ::: "memory");
    __syncthreads();
    float4 acc0 = {0,0,0,0}, acc1 = {0,0,0,0}, acc2 = {0,0,0,0}, acc3 = {0,0,0,0};
    const float4* xr = (const float4*)(xs) + (size_t)(4 * rg) * 64;
    const float* Wc = W + 4 * cg;
#pragma unroll 4
    for (int k4 = 0; k4 < 64; ++k4) {
      const float4 w0 = *(const float4*)(Wc + (k4 * 4 + 0) * 128);
      const float4 w1 = *(const float4*)(Wc + (k4 * 4 + 1) * 128);
      const float4 w2 = *(const float4*)(Wc + (k4 * 4 + 2) * 128);
      const float4 w3 = *(const float4*)(Wc + (k4 * 4 + 3) * 128);
      const float4 x0 = xr[0 * 64 + k4], x1 = xr[1 * 64 + k4];
      const float4 x2 = xr[2 * 64 + k4], x3 = xr[3 * 64 + k4];
      acc0 = f4fma(x0.x, w0, f4fma(x0.y, w1, f4fma(x0.z, w2, f4fma(x0.w, w3, acc0))));
      acc1 = f4fma(x1.x, w0, f4fma(x1.y, w1, f4fma(x1.z, w2, f4fma(x1.w, w3, acc1))));
      acc2 = f4fma(x2.x, w0, f4fma(x2.y, w1, f4fma(x2.z, w2, f4fma(x2.w, w3, acc2))));
      acc3 = f4fma(x3.x, w0, f4fma(x3.y, w1, f4fma(x3.z, w2, f4fma(x3.w, w3, acc3))));
    }
    __syncthreads();
    float4 accs[4] = {acc0, acc1, acc2, acc3};
#pragma unroll
    for (int i = 0; i < 4; ++i) {
      const int row = row0 + 4 * rg + i;
      if (row < M) {
        const float4 eq = *(const float4*)(emb + (size_t)ids[row] * 128 + 4 * cg);
        float4 v = accs[i];
        v.x += bq.x + eq.x; v.y += bq.y + eq.y;
        v.z += bq.z + eq.z; v.w += bq.w + eq.w;
        *(float4*)(out + (size_t)row * 128 + 4 * cg) = v;
      }
    }
  }
}

// ------- out[m] = AGG[m]@Wl + Xd[m]@Wr + b, opt relu (AGG pre-normalized) -------
__global__ __launch_bounds__(256) void k_sage(const float* __restrict__ AGG,
    const float* __restrict__ Xd, const float* __restrict__ Wl,
    const float* __restrict__ Wr, const float* __restrict__ b,
    float* __restrict__ out, int M, int dorelu) {
  __shared__ float xs[32 * 256];  // row = [agg(128) | x(128)]
  const int t = threadIdx.x, cg = t & 31, rg = t >> 5;
  const int lane = t & 63, wv = t >> 6;
  const float4 bq = *(const float4*)(b + 4 * cg);
  const int ntiles = (M + 31) >> 5;
  for (int tile = blockIdx.x; tile < ntiles; tile += gridDim.x) {
    const int row0 = tile << 5;
#pragma unroll
    for (int r = 0; r < 8; ++r) {
      int row = row0 + wv * 8 + r;
      row = row < M ? row : M - 1;
      const float* src = (lane < 32)
          ? AGG + (size_t)row * 128 + lane * 4
          : Xd + (size_t)row * 128 + (lane - 32) * 4;
      gl_lds16(src, xs + (wv * 8 + r) * 256);
    }
    asm volatile("s_waitcnt vmcnt(0)" ::: "memory");
    __syncthreads();
    float4 acc0 = {0,0,0,0}, acc1 = {0,0,0,0}, acc2 = {0,0,0,0}, acc3 = {0,0,0,0};
    const float4* xr = (const float4*)(xs) + (size_t)(4 * rg) * 64;
    const float* Wlc = Wl + 4 * cg;
    const float* Wrc = Wr + 4 * cg;
#pragma unroll 4
    for (int k4 = 0; k4 < 32; ++k4) {   // agg half -> Wl
      const float4 w0 = *(const float4*)(Wlc + (k4 * 4 + 0) * 128);
      const float4 w1 = *(const float4*)(Wlc + (k4 * 4 + 1) * 128);
      const float4 w2 = *(const float4*)(Wlc + (k4 * 4 + 2) * 128);
      const float4 w3 = *(const float4*)(Wlc + (k4 * 4 + 3) * 128);
      const float4 x0 = xr[0 * 64 + k4], x1 = xr[1 * 64 + k4];
      const float4 x2 = xr[2 * 64 + k4], x3 = xr[3 * 64 + k4];
      acc0 = f4fma(x0.x, w0, f4fma(x0.y, w1, f4fma(x0.z, w2, f4fma(x0.w, w3, acc0))));
      acc1 = f4fma(x1.x, w0, f4fma(x1.y, w1, f4fma(x1.z, w2, f4fma(x1.w, w3, acc1))));
      acc2 = f4fma(x2.x, w0, f4fma(x2.y, w1, f4fma(x2.z, w2, f4fma(x2.w, w3, acc2))));
      acc3 = f4fma(x3.x, w0, f4fma(x3.y, w1, f4fma(x3.z, w2, f4fma(x3.w, w3, acc3))));
    }
#pragma unroll 4
    for (int k4 = 32; k4 < 64; ++k4) {  // x half -> Wr
      const float4 w0 = *(const float4*)(Wrc + ((k4 - 32) * 4 + 0) * 128);
      const float4 w1 = *(const float4*)(Wrc + ((k4 - 32) * 4 + 1) * 128);
      const float4 w2 = *(const float4*)(Wrc + ((k4 - 32) * 4 + 2) * 128);
      const float4 w3 = *(const float4*)(Wrc + ((k4 - 32) * 4 + 3) * 128);
      const float4 x0 = xr[0 * 64 + k4], x1 = xr[1 * 64 + k4];
      const float4 x2 = xr[2 * 64 + k4], x3 = xr[3 * 64 + k4];
      acc0 = f4fma(x0.x, w0, f4fma(x0.y, w1, f4fma(x0.z, w2, f4fma(x0.w, w3, acc0))));
      acc1 = f4fma(x1.x, w0, f4fma(x1.y, w1, f4fma(x1.z, w2, f4fma(x1.w, w3, acc1))));
      acc2 = f4fma(x2.x, w0, f4fma(x2.y, w1, f4fma(x2.z, w2, f4fma(x2.w, w3, acc2))));
      acc3 = f4fma(x3.x, w0, f4fma(x3.y, w1, f4fma(x3.z, w2, f4fma(x3.w, w3, acc3))));
    }
    __syncthreads();
    float4 accs[4] = {acc0, acc1, acc2, acc3};
#pragma unroll
    for (int i = 0; i < 4; ++i) {
      const int row = row0 + 4 * rg + i;
      if (row < M) {
        float4 v = accs[i];
        v.x += bq.x; v.y += bq.y; v.z += bq.z; v.w += bq.w;
        if (dorelu) {
          v.x = fmaxf(v.x, 0.f); v.y = fmaxf(v.y, 0.f);
          v.z = fmaxf(v.z, 0.f); v.w = fmaxf(v.w, 0.f);
        }
        *(float4*)(out + (size_t)row * 128 + 4 * cg) = v;
      }
    }
  }
}

// ---------------- out[l] = W2 . relu(concat(OP[LP[l]],OS[LS[l]])@W + b1) + b2 ----------------
__global__ __launch_bounds__(256) void k_cls(const float* __restrict__ OP,
    const float* __restrict__ OS, const int* __restrict__ LP,
    const int* __restrict__ LS, const float* __restrict__ W,
    const float* __restrict__ b1, const float* __restrict__ W2,
    const float* __restrict__ b2, float* __restrict__ out, int M) {
  __shared__ float xs[32 * 256];  // row = [o_p(128) | o_s(128)]
  const int t = threadIdx.x, cg = t & 31, rg = t >> 5;
  const int lane = t & 63, wv = t >> 6;
  const float4 b1q = *(const float4*)(b1 + 4 * cg);
  const float4 w2q = *(const float4*)(W2 + 4 * cg);
  const float b2v = b2[0];
  const int ntiles = (M + 31) >> 5;
  for (int tile = blockIdx.x; tile < ntiles; tile += gridDim.x) {
    const int row0 = tile << 5;
#pragma unroll
    for (int r = 0; r < 8; ++r) {
      int row = row0 + wv * 8 + r;
      row = row < M ? row : M - 1;
      const float* src = (lane < 32)
          ? OP + (size_t)LP[row] * 128 + lane * 4
          : OS + (size_t)LS[row] * 128 + (lane - 32) * 4;
      gl_lds16(src, xs + (wv * 8 + r) * 256);
    }
    asm volatile("s_waitcnt vmcnt(0)" ::: "memory");
    __syncthreads();
    float4 acc0 = {0,0,0,0}, acc1 = {0,0,0,0}, acc2 = {0,0,0,0}, acc3 = {0,0,0,0};
    const float4* xr = (const float4*)(xs) + (size_t)(4 * rg) * 64;
    const float* Wc = W + 4 * cg;
#pragma unroll 4
    for (int k4 = 0; k4 < 64; ++k4) {
      const float4 w0 = *(const float4*)(Wc + (k4 * 4 + 0) * 128);
      const float4 w1 = *(const float4*)(Wc + (k4 * 4 + 1) * 128);
      const float4 w2 = *(const float4*)(Wc + (k4 * 4 + 2) * 128);
      const float4 w3 = *(const float4*)(Wc + (k4 * 4 + 3) * 128);
      const float4 x0 = xr[0 * 64 + k4], x1 = xr[1 * 64 + k4];
      const float4 x2 = xr[2 * 64 + k4], x3 = xr[3 * 64 + k4];
      acc0 = f4fma(x0.x, w0, f4fma(x0.y, w1, f4fma(x0.z, w2, f4fma(x0.w, w3, acc0))));
      acc1 = f4fma(x1.x, w0, f4fma(x1.y, w1, f4fma(x1.z, w2, f4fma(x1.w, w3, acc1))));
      acc2 = f4fma(x2.x, w0, f4fma(x2.y, w1, f4fma(x2.z, w2, f4fma(x2.w, w3, acc2))));
      acc3 = f4fma(x3.x, w0, f4fma(x3.y, w1, f4fma(x3.z, w2, f4fma(x3.w, w3, acc3))));
    }
    __syncthreads();
    // h = relu(acc + b1) ; v = h . W2 ; each row's 128 cols live in one 32-lane half
    float4 accs[4] = {acc0, acc1, acc2, acc3};
#pragma unroll
    for (int i = 0; i < 4; ++i) {
      float4 h = accs[i];
      float v = fmaxf(h.x + b1q.x, 0.f) * w2q.x + fmaxf(h.y + b1q.y, 0.f) * w2q.y +
                fmaxf(h.z + b1q.z, 0.f) * w2q.z + fmaxf(h.w + b1q.w, 0.f) * w2q.w;
#pragma unroll
      for (int o = 16; o >= 1; o >>= 1) v += __shfl_xor(v, o);
      const int row = row0 + 4 * rg + i;
      if (cg == 0 && row < M) out[row] = v + b2v;
    }
  }
}

extern "C" void kernel_launch(void* const* d_in, const int* in_sizes, int n_in,
                              void* d_out, int out_size, void* d_ws, size_t ws_size,
                              hipStream_t stream) {
  const float* x_paper     = (const float*)d_in[0];
  const float* x_software  = (const float*)d_in[1];
  const int*   paper_id    = (const int*)d_in[2];
  const int*   software_id = (const int*)d_in[3];
  const int*   edge_src    = (const int*)d_in[4];
  const int*   edge_dst    = (const int*)d_in[5];
  const int*   lbl_paper   = (const int*)d_in[6];
  const int*   lbl_soft    = (const int*)d_in[7];
  const float* paper_emb   = (const float*)d_in[8];
  const float* soft_emb    = (const float*)d_in[9];
  const float* Wp = (const float*)d_in[10]; const float* bp = (const float*)d_in[11];
  const float* Ws = (const float*)d_in[12]; const float* bs = (const float*)d_in[13];
  const float* Wl1_ps = (const float*)d_in[14]; const float* bl1_ps = (const float*)d_in[15];
  const float* Wr1_ps = (const float*)d_in[16];
  const float* Wl1_sp = (const float*)d_in[17]; const float* bl1_sp = (const float*)d_in[18];
  const float* Wr1_sp = (const float*)d_in[19];
  const float* Wl2_ps = (const float*)d_in[20]; const float* bl2_ps = (const float*)d_in[21];
  const float* Wr2_ps = (const float*)d_in[22];
  const float* Wl2_sp = (const float*)d_in[23]; const float* bl2_sp = (const float*)d_in[24];
  const float* Wr2_sp = (const float*)d_in[25];
  const float* Wc1 = (const float*)d_in[26]; const float* bc1 = (const float*)d_in[27];
  const float* Wc2 = (const float*)d_in[28]; const float* bc2 = (const float*)d_in[29];
  float* outp = (float*)d_out;

  // workspace layout (floats)
  float* ws    = (float*)d_ws;
  float* x_p   = ws;                 // 12,800,000  (reused as o_p)
  float* x_s   = ws + 12800000;      //  1,280,000  (reused as o_s)
  float* h_p   = ws + 14080000;      // 12,800,000
  float* h_s   = ws + 26880000;      //  1,280,000
  float* agg_p = ws + 28160000;      // 12,800,000
  float* agg_s = ws + 40960000;      //  1,280,000  -> ends 42,240,000
  int*   deg_p = (int*)(ws + 42240000);  // 100,000 (aliased as cur_p after scan)
  int*   deg_s = deg_p + 100000;         //  10,000 (aliased as cur_s)
  int*   off_p = deg_s + 10000;          // 100,001
  int*   off_s = off_p + 100001;         //  10,001
  int*   bsum  = off_s + 10001;          //   1,024
  int*   csr_p = bsum + 1024;            // 500,000 (dst ids grouped by paper src)
  int*   csr_s = csr_p + 500000;         // 500,000 (src ids grouped by software dst)
  float* o_p = x_p;
  float* o_s = x_s;

  // ---- CSR build (once; reused by both layers) ----
  hipMemsetAsync(deg_p, 0, (size_t)110000 * 4, stream);  // deg_p + deg_s contiguous
  k_hist<<<1024, 256, 0, stream>>>(edge_src, edge_dst, deg_p, deg_s);
  k_scan1<<<98, 1024, 0, stream>>>(deg_p, NPn, off_p, bsum);
  k_scan2<<<1, 1024, 0, stream>>>(bsum, 98, off_p, NPn);
  k_scan3<<<391, 256, 0, stream>>>(off_p, deg_p, bsum, NPn);   // cur_p := deg_p
  k_scan1<<<10, 1024, 0, stream>>>(deg_s, NSn, off_s, bsum);
  k_scan2<<<1, 1024, 0, stream>>>(bsum, 10, off_s, NSn);
  k_scan3<<<40, 256, 0, stream>>>(off_s, deg_s, bsum, NSn);    // cur_s := deg_s
  k_fill<<<1024, 256, 0, stream>>>(edge_src, edge_dst, deg_p, deg_s, csr_p, csr_s);

  // ---- input fusion ----
  k_input<<<1024, 256, 0, stream>>>(x_paper, Wp, bp, paper_emb, paper_id, x_p, NPn);
  k_input<<<313, 256, 0, stream>>>(x_software, Ws, bs, soft_emb, software_id, x_s, NSn);

  // ---- layer 1 (gather-aggregate, pre-normalized) ----
  k_gather<<<1250, 256, 0, stream>>>(x_p, off_s, csr_s, agg_s, NSn);
  k_gather<<<4096, 256, 0, stream>>>(x_s, off_p, csr_p, agg_p, NPn);
  k_sage<<<313, 256, 0, stream>>>(agg_s, x_s, Wl1_ps, Wr1_ps, bl1_ps, h_s, NSn, 1);
  k_sage<<<1024, 256, 0, stream>>>(agg_p, x_p, Wl1_sp, Wr1_sp, bl1_sp, h_p, NPn, 1);

  // ---- layer 2 ----
  k_gather<<<1250, 256, 0, stream>>>(h_p, off_s, csr_s, agg_s, NSn);
  k_gather<<<4096, 256, 0, stream>>>(h_s, off_p, csr_p, agg_p, NPn);
  k_sage<<<313, 256, 0, stream>>>(agg_s, h_s, Wl2_ps, Wr2_ps, bl2_ps, o_s, NSn, 0);
  k_sage<<<1024, 256, 0, stream>>>(agg_p, h_p, Wl2_sp, Wr2_sp, bl2_sp, o_p, NPn, 0);

  // ---- classifier ----
  k_cls<<<1024, 256, 0, stream>>>(o_p, o_s, lbl_paper, lbl_soft, Wc1, bc1, Wc2, bc2,
                                  outp, NLn);
}

// Round 5
// 974.185 us; speedup vs baseline: 4.8651x; 1.2066x over previous
//
#include <hip/hip_runtime.h>

#define NPn 100000
#define NSn 10000
#define EMBn 256
#define HIDn 128
#define NEn 500000
#define NLn 200000

// async global->LDS: per-lane global src, wave-uniform LDS dest (+lane*16B)
__device__ __forceinline__ void gl_lds16(const float* g, float* l) {
  __builtin_amdgcn_global_load_lds(
      (const __attribute__((address_space(1))) void*)g,
      (__attribute__((address_space(3))) void*)l, 16, 0, 0);
}

__device__ __forceinline__ float4 f4fma(float s, float4 w, float4 a) {
  a.x = fmaf(s, w.x, a.x); a.y = fmaf(s, w.y, a.y);
  a.z = fmaf(s, w.z, a.z); a.w = fmaf(s, w.w, a.w);
  return a;
}

// ---------------- degree histogram ----------------
__global__ void k_hist(const int* __restrict__ es, const int* __restrict__ ed,
                       int* __restrict__ dp, int* __restrict__ dsw) {
  const int stride = gridDim.x * blockDim.x;
  for (int i = blockIdx.x * blockDim.x + threadIdx.x; i < NEn; i += stride) {
    atomicAdd(&dp[es[i]], 1);
    atomicAdd(&dsw[ed[i]], 1);
  }
}

// ---------------- scan pass 1: per-block exclusive scan + block totals ----------------
__global__ __launch_bounds__(1024) void k_scan1(const int* __restrict__ deg, int n,
    int* __restrict__ off, int* __restrict__ bsum) {
  __shared__ int wsum[16];
  const int t = threadIdx.x, lane = t & 63, w = t >> 6;
  const int i = blockIdx.x * 1024 + t;
  const int v = (i < n) ? deg[i] : 0;
  int x = v;
#pragma unroll
  for (int o = 1; o < 64; o <<= 1) { int y = __shfl_up(x, o); if (lane >= o) x += y; }
  if (lane == 63) wsum[w] = x;
  __syncthreads();
  if (t < 16) {
    int s = wsum[t];
#pragma unroll
    for (int o = 1; o < 16; o <<= 1) { int y = __shfl_up(s, o); if (t >= o) s += y; }
    wsum[t] = s;
  }
  __syncthreads();
  const int excl = (x - v) + (w ? wsum[w - 1] : 0);
  if (i < n) off[i] = excl;
  if (t == 1023) bsum[blockIdx.x] = excl + v;  // block total
}

// ---------------- scan pass 2: single-block exclusive scan of block sums ----------------
__global__ __launch_bounds__(1024) void k_scan2(int* __restrict__ bsum, int nb,
    int* __restrict__ off, int n) {
  __shared__ int wsum[16];
  const int t = threadIdx.x, lane = t & 63, w = t >> 6;
  const int v = (t < nb) ? bsum[t] : 0;
  int x = v;
#pragma unroll
  for (int o = 1; o < 64; o <<= 1) { int y = __shfl_up(x, o); if (lane >= o) x += y; }
  if (lane == 63) wsum[w] = x;
  __syncthreads();
  if (t < 16) {
    int s = wsum[t];
#pragma unroll
    for (int o = 1; o < 16; o <<= 1) { int y = __shfl_up(s, o); if (t >= o) s += y; }
    wsum[t] = s;
  }
  __syncthreads();
  const int excl = (x - v) + (w ? wsum[w - 1] : 0);
  if (t < nb) bsum[t] = excl;
  if (t == nb - 1) off[n] = excl + v;  // grand total = NEn
}

// ---------------- scan pass 3: add block bases; init cursors ----------------
__global__ void k_scan3(int* __restrict__ off, int* __restrict__ cur,
                        const int* __restrict__ bsum, int n) {
  const int i = blockIdx.x * blockDim.x + threadIdx.x;
  if (i < n) {
    const int o = off[i] + bsum[i >> 10];
    off[i] = o;
    cur[i] = o;
  }
}

// ---------------- CSR fill (both directions in one pass) ----------------
__global__ void k_fill(const int* __restrict__ es, const int* __restrict__ ed,
                       int* __restrict__ cur_p, int* __restrict__ cur_s,
                       int* __restrict__ csr_p, int* __restrict__ csr_s) {
  const int stride = gridDim.x * blockDim.x;
  for (int e = blockIdx.x * blockDim.x + threadIdx.x; e < NEn; e += stride) {
    const int s = es[e], d = ed[e];
    const int ps = atomicAdd(&cur_s[d], 1);
    csr_s[ps] = s;
    const int pp = atomicAdd(&cur_p[s], 1);
    csr_p[pp] = d;
  }
}

// ---- weight pre-composition: W' = A @ Bhalf, b' = bin @ Bhalf (layer2 is linear) ----
// grid = 4*65 blocks of 256. comp 0: Wl2_sp@top, 1: Wr2_sp@top, 2: Wl2_ps@bot, 3: Wr2_ps@bot.
__global__ __launch_bounds__(256) void k_wcomp(
    const float* __restrict__ Wl_sp, const float* __restrict__ Wr_sp,
    const float* __restrict__ Wl_ps, const float* __restrict__ Wr_ps,
    const float* __restrict__ bl_sp, const float* __restrict__ bl_ps,
    const float* __restrict__ Wc1,
    float* __restrict__ Wlp, float* __restrict__ Wrp,
    float* __restrict__ Wls, float* __restrict__ Wrs,
    float* __restrict__ bpc, float* __restrict__ bsc) {
  const int comp = blockIdx.x / 65, sub = blockIdx.x % 65;
  const float* A; const float* B; float* C; const float* bin; float* bout;
  switch (comp) {
    case 0:  A = Wl_sp; B = Wc1;         C = Wlp; bin = bl_sp;  bout = bpc; break;
    case 1:  A = Wr_sp; B = Wc1;         C = Wrp; bin = nullptr; bout = nullptr; break;
    case 2:  A = Wl_ps; B = Wc1 + 16384; C = Wls; bin = bl_ps;  bout = bsc; break;
    default: A = Wr_ps; B = Wc1 + 16384; C = Wrs; bin = nullptr; bout = nullptr; break;
  }
  const int t = threadIdx.x;
  if (sub < 64) {
    const int idx = sub * 256 + t, r = idx >> 7, c = idx & 127;
    float acc = 0.f;
#pragma unroll 8
    for (int k = 0; k < 128; ++k) acc = fmaf(A[r * 128 + k], B[k * 128 + c], acc);
    C[idx] = acc;
  } else if (bin != nullptr && t < 128) {
    float acc = 0.f;
#pragma unroll 8
    for (int k = 0; k < 128; ++k) acc = fmaf(bin[k], B[k * 128 + t], acc);
    bout[t] = acc;
  }
}

// ------- gather-aggregate: agg[d] = mean_{e in CSR[d]} X[lst[e]]  (pre-normalized) -------
__global__ __launch_bounds__(256) void k_gather(const float* __restrict__ X,
    const int* __restrict__ off, const int* __restrict__ lst,
    float* __restrict__ agg, int n) {
  const int q = threadIdx.x & 31;
  const int g0 = (blockIdx.x * blockDim.x + threadIdx.x) >> 5;
  const int gs = (gridDim.x * blockDim.x) >> 5;
  for (int d = g0; d < n; d += gs) {
    const int s0 = off[d], s1 = off[d + 1];
    float4 a0 = make_float4(0.f, 0.f, 0.f, 0.f);
    float4 a1 = make_float4(0.f, 0.f, 0.f, 0.f);
    int e = s0;
    for (; e + 2 <= s1; e += 2) {
      const int sa = lst[e], sb = lst[e + 1];
      const float4 va = ((const float4*)X)[(size_t)sa * 32 + q];
      const float4 vb = ((const float4*)X)[(size_t)sb * 32 + q];
      a0.x += va.x; a0.y += va.y; a0.z += va.z; a0.w += va.w;
      a1.x += vb.x; a1.y += vb.y; a1.z += vb.z; a1.w += vb.w;
    }
    if (e < s1) {
      const int sa = lst[e];
      const float4 va = ((const float4*)X)[(size_t)sa * 32 + q];
      a0.x += va.x; a0.y += va.y; a0.z += va.z; a0.w += va.w;
    }
    const int dg = s1 - s0;
    const float inv = 1.0f / (float)(dg > 1 ? dg : 1);
    float4 r;
    r.x = (a0.x + a1.x) * inv; r.y = (a0.y + a1.y) * inv;
    r.z = (a0.z + a1.z) * inv; r.w = (a0.w + a1.w) * inv;
    ((float4*)agg)[(size_t)d * 32 + q] = r;
  }
}

// ============ GEMM kernels: 32-row tile, thread = 4 rows x 4 cols ============

// ---------------- out[m] = X[m]@W + b + emb[ids[m]]  (X:[M,256], W:[256,128]) ----------------
__global__ __launch_bounds__(256) void k_input(const float* __restrict__ X,
    const float* __restrict__ W, const float* __restrict__ b,
    const float* __restrict__ emb, const int* __restrict__ ids,
    float* __restrict__ out, int M) {
  __shared__ float xs[32 * 256];
  const int t = threadIdx.x, cg = t & 31, rg = t >> 5;
  const int lane = t & 63, wv = t >> 6;
  const float4 bq = *(const float4*)(b + 4 * cg);
  const int ntiles = (M + 31) >> 5;
  for (int tile = blockIdx.x; tile < ntiles; tile += gridDim.x) {
    const int row0 = tile << 5;
#pragma unroll
    for (int r = 0; r < 8; ++r) {
      int row = row0 + wv * 8 + r;
      row = row < M ? row : M - 1;
      gl_lds16(X + (size_t)row * 256 + lane * 4, xs + (wv * 8 + r) * 256);
    }
    asm volatile("s_waitcnt vmcnt(0)" ::: "memory");
    __syncthreads();
    float4 acc0 = {0,0,0,0}, acc1 = {0,0,0,0}, acc2 = {0,0,0,0}, acc3 = {0,0,0,0};
    const float4* xr = (const float4*)(xs) + (size_t)(4 * rg) * 64;
    const float* Wc = W + 4 * cg;
#pragma unroll 4
    for (int k4 = 0; k4 < 64; ++k4) {
      const float4 w0 = *(const float4*)(Wc + (k4 * 4 + 0) * 128);
      const float4 w1 = *(const float4*)(Wc + (k4 * 4 + 1) * 128);
      const float4 w2 = *(const float4*)(Wc + (k4 * 4 + 2) * 128);
      const float4 w3 = *(const float4*)(Wc + (k4 * 4 + 3) * 128);
      const float4 x0 = xr[0 * 64 + k4], x1 = xr[1 * 64 + k4];
      const float4 x2 = xr[2 * 64 + k4], x3 = xr[3 * 64 + k4];
      acc0 = f4fma(x0.x, w0, f4fma(x0.y, w1, f4fma(x0.z, w2, f4fma(x0.w, w3, acc0))));
      acc1 = f4fma(x1.x, w0, f4fma(x1.y, w1, f4fma(x1.z, w2, f4fma(x1.w, w3, acc1))));
      acc2 = f4fma(x2.x, w0, f4fma(x2.y, w1, f4fma(x2.z, w2, f4fma(x2.w, w3, acc2))));
      acc3 = f4fma(x3.x, w0, f4fma(x3.y, w1, f4fma(x3.z, w2, f4fma(x3.w, w3, acc3))));
    }
    __syncthreads();
    float4 accs[4] = {acc0, acc1, acc2, acc3};
#pragma unroll
    for (int i = 0; i < 4; ++i) {
      const int row = row0 + 4 * rg + i;
      if (row < M) {
        const float4 eq = *(const float4*)(emb + (size_t)ids[row] * 128 + 4 * cg);
        float4 v = accs[i];
        v.x += bq.x + eq.x; v.y += bq.y + eq.y;
        v.z += bq.z + eq.z; v.w += bq.w + eq.w;
        *(float4*)(out + (size_t)row * 128 + 4 * cg) = v;
      }
    }
  }
}

// ------- out[m] = AGG[m]@Wl + Xd[m]@Wr + b, opt relu (AGG pre-normalized) -------
__global__ __launch_bounds__(256) void k_sage(const float* __restrict__ AGG,
    const float* __restrict__ Xd, const float* __restrict__ Wl,
    const float* __restrict__ Wr, const float* __restrict__ b,
    float* __restrict__ out, int M, int dorelu) {
  __shared__ float xs[32 * 256];  // row = [agg(128) | x(128)]
  const int t = threadIdx.x, cg = t & 31, rg = t >> 5;
  const int lane = t & 63, wv = t >> 6;
  const float4 bq = *(const float4*)(b + 4 * cg);
  const int ntiles = (M + 31) >> 5;
  for (int tile = blockIdx.x; tile < ntiles; tile += gridDim.x) {
    const int row0 = tile << 5;
#pragma unroll
    for (int r = 0; r < 8; ++r) {
      int row = row0 + wv * 8 + r;
      row = row < M ? row : M - 1;
      const float* src = (lane < 32)
          ? AGG + (size_t)row * 128 + lane * 4
          : Xd + (size_t)row * 128 + (lane - 32) * 4;
      gl_lds16(src, xs + (wv * 8 + r) * 256);
    }
    asm volatile("s_waitcnt vmcnt(0)" ::: "memory");
    __syncthreads();
    float4 acc0 = {0,0,0,0}, acc1 = {0,0,0,0}, acc2 = {0,0,0,0}, acc3 = {0,0,0,0};
    const float4* xr = (const float4*)(xs) + (size_t)(4 * rg) * 64;
    const float* Wlc = Wl + 4 * cg;
    const float* Wrc = Wr + 4 * cg;
#pragma unroll 4
    for (int k4 = 0; k4 < 32; ++k4) {   // agg half -> Wl
      const float4 w0 = *(const float4*)(Wlc + (k4 * 4 + 0) * 128);
      const float4 w1 = *(const float4*)(Wlc + (k4 * 4 + 1) * 128);
      const float4 w2 = *(const float4*)(Wlc + (k4 * 4 + 2) * 128);
      const float4 w3 = *(const float4*)(Wlc + (k4 * 4 + 3) * 128);
      const float4 x0 = xr[0 * 64 + k4], x1 = xr[1 * 64 + k4];
      const float4 x2 = xr[2 * 64 + k4], x3 = xr[3 * 64 + k4];
      acc0 = f4fma(x0.x, w0, f4fma(x0.y, w1, f4fma(x0.z, w2, f4fma(x0.w, w3, acc0))));
      acc1 = f4fma(x1.x, w0, f4fma(x1.y, w1, f4fma(x1.z, w2, f4fma(x1.w, w3, acc1))));
      acc2 = f4fma(x2.x, w0, f4fma(x2.y, w1, f4fma(x2.z, w2, f4fma(x2.w, w3, acc2))));
      acc3 = f4fma(x3.x, w0, f4fma(x3.y, w1, f4fma(x3.z, w2, f4fma(x3.w, w3, acc3))));
    }
#pragma unroll 4
    for (int k4 = 32; k4 < 64; ++k4) {  // x half -> Wr
      const float4 w0 = *(const float4*)(Wrc + ((k4 - 32) * 4 + 0) * 128);
      const float4 w1 = *(const float4*)(Wrc + ((k4 - 32) * 4 + 1) * 128);
      const float4 w2 = *(const float4*)(Wrc + ((k4 - 32) * 4 + 2) * 128);
      const float4 w3 = *(const float4*)(Wrc + ((k4 - 32) * 4 + 3) * 128);
      const float4 x0 = xr[0 * 64 + k4], x1 = xr[1 * 64 + k4];
      const float4 x2 = xr[2 * 64 + k4], x3 = xr[3 * 64 + k4];
      acc0 = f4fma(x0.x, w0, f4fma(x0.y, w1, f4fma(x0.z, w2, f4fma(x0.w, w3, acc0))));
      acc1 = f4fma(x1.x, w0, f4fma(x1.y, w1, f4fma(x1.z, w2, f4fma(x1.w, w3, acc1))));
      acc2 = f4fma(x2.x, w0, f4fma(x2.y, w1, f4fma(x2.z, w2, f4fma(x2.w, w3, acc2))));
      acc3 = f4fma(x3.x, w0, f4fma(x3.y, w1, f4fma(x3.z, w2, f4fma(x3.w, w3, acc3))));
    }
    __syncthreads();
    float4 accs[4] = {acc0, acc1, acc2, acc3};
#pragma unroll
    for (int i = 0; i < 4; ++i) {
      const int row = row0 + 4 * rg + i;
      if (row < M) {
        float4 v = accs[i];
        v.x += bq.x; v.y += bq.y; v.z += bq.z; v.w += bq.w;
        if (dorelu) {
          v.x = fmaxf(v.x, 0.f); v.y = fmaxf(v.y, 0.f);
          v.z = fmaxf(v.z, 0.f); v.w = fmaxf(v.w, 0.f);
        }
        *(float4*)(out + (size_t)row * 128 + 4 * cg) = v;
      }
    }
  }
}

// ---- classifier lite: out[l] = relu(PP[LP[l]] + PS[LS[l]] + b1) . W2 + b2 ----
// one 32-lane group per label; 2 coalesced 512B row reads + shfl reduce; no LDS.
__global__ __launch_bounds__(256) void k_cls2(const float* __restrict__ PP,
    const float* __restrict__ PS, const int* __restrict__ LP,
    const int* __restrict__ LS, const float* __restrict__ b1,
    const float* __restrict__ W2, const float* __restrict__ b2,
    float* __restrict__ out, int M) {
  const int t = threadIdx.x, q = t & 31;
  const int g0 = (blockIdx.x * blockDim.x + t) >> 5;
  const int gs = (gridDim.x * blockDim.x) >> 5;
  const float4 b1q = *(const float4*)(b1 + 4 * q);
  const float4 w2q = *(const float4*)(W2 + 4 * q);
  const float b2v = b2[0];
  for (int l = g0; l < M; l += gs) {
    const float4 pp = *(const float4*)(PP + (size_t)LP[l] * 128 + 4 * q);
    const float4 ps = *(const float4*)(PS + (size_t)LS[l] * 128 + 4 * q);
    float v = fmaxf(pp.x + ps.x + b1q.x, 0.f) * w2q.x
            + fmaxf(pp.y + ps.y + b1q.y, 0.f) * w2q.y
            + fmaxf(pp.z + ps.z + b1q.z, 0.f) * w2q.z
            + fmaxf(pp.w + ps.w + b1q.w, 0.f) * w2q.w;
#pragma unroll
    for (int o = 16; o >= 1; o >>= 1) v += __shfl_xor(v, o);
    if (q == 0) out[l] = v + b2v;
  }
}

extern "C" void kernel_launch(void* const* d_in, const int* in_sizes, int n_in,
                              void* d_out, int out_size, void* d_ws, size_t ws_size,
                              hipStream_t stream) {
  const float* x_paper     = (const float*)d_in[0];
  const float* x_software  = (const float*)d_in[1];
  const int*   paper_id    = (const int*)d_in[2];
  const int*   software_id = (const int*)d_in[3];
  const int*   edge_src    = (const int*)d_in[4];
  const int*   edge_dst    = (const int*)d_in[5];
  const int*   lbl_paper   = (const int*)d_in[6];
  const int*   lbl_soft    = (const int*)d_in[7];
  const float* paper_emb   = (const float*)d_in[8];
  const float* soft_emb    = (const float*)d_in[9];
  const float* Wp = (const float*)d_in[10]; const float* bp = (const float*)d_in[11];
  const float* Ws = (const float*)d_in[12]; const float* bs = (const float*)d_in[13];
  const float* Wl1_ps = (const float*)d_in[14]; const float* bl1_ps = (const float*)d_in[15];
  const float* Wr1_ps = (const float*)d_in[16];
  const float* Wl1_sp = (const float*)d_in[17]; const float* bl1_sp = (const float*)d_in[18];
  const float* Wr1_sp = (const float*)d_in[19];
  const float* Wl2_ps = (const float*)d_in[20]; const float* bl2_ps = (const float*)d_in[21];
  const float* Wr2_ps = (const float*)d_in[22];
  const float* Wl2_sp = (const float*)d_in[23]; const float* bl2_sp = (const float*)d_in[24];
  const float* Wr2_sp = (const float*)d_in[25];
  const float* Wc1 = (const float*)d_in[26]; const float* bc1 = (const float*)d_in[27];
  const float* Wc2 = (const float*)d_in[28]; const float* bc2 = (const float*)d_in[29];
  float* outp = (float*)d_out;

  // workspace layout (floats)
  float* ws    = (float*)d_ws;
  float* x_p   = ws;                 // 12,800,000  (reused as proj_p)
  float* x_s   = ws + 12800000;      //  1,280,000  (reused as proj_s)
  float* h_p   = ws + 14080000;      // 12,800,000
  float* h_s   = ws + 26880000;      //  1,280,000
  float* agg_p = ws + 28160000;      // 12,800,000
  float* agg_s = ws + 40960000;      //  1,280,000  -> ends 42,240,000
  int*   deg_p = (int*)(ws + 42240000);  // 100,000 (aliased as cur_p after scan)
  int*   deg_s = deg_p + 100000;         //  10,000 (aliased as cur_s)
  int*   off_p = deg_s + 10000;          // 100,001
  int*   off_s = off_p + 100001;         //  10,001
  int*   bsum  = off_s + 10001;          //   1,024
  int*   csr_p = bsum + 1024;            // 500,000 (dst ids grouped by paper src)
  int*   csr_s = csr_p + 500000;         // 500,000 (src ids grouped by software dst)
  // composed layer2+classifier weights (after int region)
  float* Wlp = (float*)(csr_s + 500000); // 16384: Wl2_sp @ Wc1_top
  float* Wrp = Wlp + 16384;              // 16384: Wr2_sp @ Wc1_top
  float* Wls = Wrp + 16384;              // 16384: Wl2_ps @ Wc1_bot
  float* Wrs = Wls + 16384;              // 16384: Wr2_ps @ Wc1_bot
  float* bpc = Wrs + 16384;              //   128: bl2_sp @ Wc1_top
  float* bsc = bpc + 128;                //   128: bl2_ps @ Wc1_bot
  float* proj_p = x_p;
  float* proj_s = x_s;

  // ---- weight pre-composition (layer 2 is linear -> fold classifier GEMM away) ----
  k_wcomp<<<260, 256, 0, stream>>>(Wl2_sp, Wr2_sp, Wl2_ps, Wr2_ps, bl2_sp, bl2_ps,
                                   Wc1, Wlp, Wrp, Wls, Wrs, bpc, bsc);

  // ---- CSR build (once; reused by both layers) ----
  hipMemsetAsync(deg_p, 0, (size_t)110000 * 4, stream);  // deg_p + deg_s contiguous
  k_hist<<<1024, 256, 0, stream>>>(edge_src, edge_dst, deg_p, deg_s);
  k_scan1<<<98, 1024, 0, stream>>>(deg_p, NPn, off_p, bsum);
  k_scan2<<<1, 1024, 0, stream>>>(bsum, 98, off_p, NPn);
  k_scan3<<<391, 256, 0, stream>>>(off_p, deg_p, bsum, NPn);   // cur_p := deg_p
  k_scan1<<<10, 1024, 0, stream>>>(deg_s, NSn, off_s, bsum);
  k_scan2<<<1, 1024, 0, stream>>>(bsum, 10, off_s, NSn);
  k_scan3<<<40, 256, 0, stream>>>(off_s, deg_s, bsum, NSn);    // cur_s := deg_s
  k_fill<<<1024, 256, 0, stream>>>(edge_src, edge_dst, deg_p, deg_s, csr_p, csr_s);

  // ---- input fusion ----
  k_input<<<1024, 256, 0, stream>>>(x_paper, Wp, bp, paper_emb, paper_id, x_p, NPn);
  k_input<<<313, 256, 0, stream>>>(x_software, Ws, bs, soft_emb, software_id, x_s, NSn);

  // ---- layer 1 (gather-aggregate, pre-normalized) ----
  k_gather<<<1250, 256, 0, stream>>>(x_p, off_s, csr_s, agg_s, NSn);
  k_gather<<<4096, 256, 0, stream>>>(x_s, off_p, csr_p, agg_p, NPn);
  k_sage<<<313, 256, 0, stream>>>(agg_s, x_s, Wl1_ps, Wr1_ps, bl1_ps, h_s, NSn, 1);
  k_sage<<<1024, 256, 0, stream>>>(agg_p, x_p, Wl1_sp, Wr1_sp, bl1_sp, h_p, NPn, 1);

  // ---- layer 2 (composed weights -> directly produce classifier projections) ----
  k_gather<<<1250, 256, 0, stream>>>(h_p, off_s, csr_s, agg_s, NSn);
  k_gather<<<4096, 256, 0, stream>>>(h_s, off_p, csr_p, agg_p, NPn);
  k_sage<<<313, 256, 0, stream>>>(agg_s, h_s, Wls, Wrs, bsc, proj_s, NSn, 0);
  k_sage<<<1024, 256, 0, stream>>>(agg_p, h_p, Wlp, Wrp, bpc, proj_p, NPn, 0);

  // ---- classifier (gather-reduce only) ----
  k_cls2<<<2048, 256, 0, stream>>>(proj_p, proj_s, lbl_paper, lbl_soft, bc1, Wc2, bc2,
                                   outp, NLn);
}